// Round 10
// baseline (262.999 us; speedup 1.0000x reference)
//
#include <hip/hip_runtime.h>
#include <hip/hip_bf16.h>

#define NTOK 4096
#define HID 2048
#define INTER 1408
#define NEXP 8
#define NPAIR 8192   // NTOK * TOP_K
#define NK1 64       // HID/32   (gemm1 BK=32)
#define NK2 44       // INTER/32 (gemm2 BK=32)
#define G1SZ 24576   // gemm1 bytes/buffer: A 128x32 (8K) + B 256x32 (16K)
#define G2SZ 16384   // gemm2 bytes/buffer: A 128x32 (8K) + B 128x32 (8K)

typedef short bf16x8 __attribute__((ext_vector_type(8)));
typedef float f32x4 __attribute__((ext_vector_type(4)));

__device__ __forceinline__ unsigned short f2bf(float f) {
  unsigned u = __builtin_bit_cast(unsigned, f);
  u += 0x7fffu + ((u >> 16) & 1u);   // round-to-nearest-even
  return (unsigned short)(u >> 16);
}
__device__ __forceinline__ float bf2f(unsigned short v) {
  return __builtin_bit_cast(float, (unsigned)v << 16);
}

__device__ __forceinline__ void gload16(const void* g, void* l) {
  __builtin_amdgcn_global_load_lds(
      (const __attribute__((address_space(1))) void*)g,
      (__attribute__((address_space(3))) void*)l, 16, 0, 0);
}

// m204 bijective XCD swizzle over the LIVE grid size nwg.
__device__ __forceinline__ int xcd_swz(int lin, int nwg) {
  int xcd = lin & 7, base = lin >> 3;
  int q = nwg >> 3, r = nwg & 7;
  return (xcd < r ? xcd * (q + 1) : r * (q + 1) + (xcd - r) * q) + base;
}

#define BAR __builtin_amdgcn_s_barrier()
#define SCHED0 __builtin_amdgcn_sched_barrier(0)
#define LGKM0 asm volatile("s_waitcnt lgkmcnt(0)" ::: "memory")
#define VM3 asm volatile("s_waitcnt vmcnt(3)" ::: "memory")
#define VM2 asm volatile("s_waitcnt vmcnt(2)" ::: "memory")
#define VM0 asm volatile("s_waitcnt vmcnt(0)" ::: "memory")
#define PRIO1 __builtin_amdgcn_s_setprio(1)
#define PRIO0 __builtin_amdgcn_s_setprio(0)

// ============ prep: block 0 routes; the rest convert hs + w1 ============
// ctrl ints: [0..7]=cnt [8..15]=off [16]=T (BM=128 tiles, T<=72)
//            [32..103]=tile_e  [104..175]=tile_mt
__global__ void k_prep(const float* __restrict__ hs, const float* __restrict__ w1,
                       unsigned short* __restrict__ dst,
                       const int* __restrict__ ids, int* __restrict__ ctrl,
                       unsigned short* __restrict__ row_token,
                       unsigned short* __restrict__ inv_row) {
  if (blockIdx.x == 0) {
    __shared__ int cnt[NEXP], cur[NEXP];
    int t = threadIdx.x;
    if (t < NEXP) cnt[t] = 0;
    __syncthreads();
    for (int p = t; p < NPAIR; p += 512) atomicAdd(&cnt[ids[p]], 1);
    __syncthreads();
    if (t == 0) {
      int acc = 0, T = 0;
      for (int e = 0; e < NEXP; ++e) {
        cur[e] = acc;
        ctrl[e] = cnt[e];
        ctrl[8 + e] = acc;
        int n = (cnt[e] + 127) >> 7;
        for (int m = 0; m < n; ++m) { ctrl[32 + T] = e; ctrl[104 + T] = m; ++T; }
        acc += cnt[e];
      }
      ctrl[16] = T;
    }
    __syncthreads();
    for (int p = t; p < NPAIR; p += 512) {
      int e = ids[p];
      int pos = atomicAdd(&cur[e], 1);
      row_token[pos] = (unsigned short)(p >> 1);
      inv_row[p] = (unsigned short)pos;
    }
    return;
  }
  const int N0 = NTOK * HID / 4;
  const int N1 = N0 + NEXP * 2 * INTER * HID / 4;
  int stride = (gridDim.x - 1) * 512;
  for (int i = (blockIdx.x - 1) * 512 + threadIdx.x; i < N1; i += stride) {
    const float* s = (i < N0) ? hs : w1;
    int o = (i < N0) ? i : i - N0;
    float4 v = reinterpret_cast<const float4*>(s)[o];
    ushort4 u;
    u.x = f2bf(v.x); u.y = f2bf(v.y); u.z = f2bf(v.z); u.w = f2bf(v.w);
    reinterpret_cast<ushort4*>(dst)[i] = u;
  }
}

// ================= GEMM1: gate_up + SwiGLU =================
// BM=128 rows x BN=128 acts (256 gate_up chans), BK=32, 8 waves (2Mx4N),
// TRIPLE-buffered LDS (3 x 24 KiB = 72 KiB) -> 2 blocks/CU, ONE barrier/iter:
//   { 8 ds_read(cur); stage(buf kt+2); sched0; 16 MFMA; vmcnt(3); lgkm0; BAR }
// stage targets buf(kt+2) == buf(kt-1), whose reads retired before iter
// kt-1's LGKM0+BAR; vmcnt(3) completes tile kt+1, leaves kt+2 in flight.
// Blocks beyond the live tile grid convert w2 fp32->bf16 (gemm2-only input).

#define G1_STAGE(BB, kt) { \
  gload16(aptr + (size_t)(kt)*32, smem + (BB) + wvb16); \
  gload16(bptr0 + (size_t)(kt)*32, smem + (BB) + 8192 + wvb16); \
  gload16(bptr1 + (size_t)(kt)*32, smem + (BB) + 16384 + wvb16); }

#define G1_RD(BB) { \
  _Pragma("unroll") for (int m_ = 0; m_ < 4; ++m_) \
    af[m_] = *(const bf16x8*)(smem + (BB) + arow + m_*1024 + swz); \
  _Pragma("unroll") for (int n_ = 0; n_ < 2; ++n_) { \
    bg[n_] = *(const bf16x8*)(smem + (BB) + brow + n_*1024 + swz); \
    bu[n_] = *(const bf16x8*)(smem + (BB) + brow + 8192 + n_*1024 + swz); } }

#define G1_MMA \
  _Pragma("unroll") for (int m_ = 0; m_ < 4; ++m_) \
  _Pragma("unroll") for (int n_ = 0; n_ < 2; ++n_) { \
    accg[m_][n_] = __builtin_amdgcn_mfma_f32_16x16x32_bf16(af[m_], bg[n_], accg[m_][n_], 0, 0, 0); \
    accu[m_][n_] = __builtin_amdgcn_mfma_f32_16x16x32_bf16(af[m_], bu[n_], accu[m_][n_], 0, 0, 0); }

__global__ __launch_bounds__(512, 4) void k_gemm1(
    const unsigned short* __restrict__ hs,
    const unsigned short* __restrict__ w1,
    const float* __restrict__ w2f,
    unsigned short* __restrict__ w2b,
    const int* __restrict__ ctrl,
    const unsigned short* __restrict__ row_token,
    unsigned short* __restrict__ act) {
  const int T = ctrl[16];
  const int nwg = T * 11;
  const int lin = blockIdx.x;
  if (lin >= nwg) {
    // ---- w2 fp32 -> bf16 convert (tail blocks, fills idle CUs) ----
    const int NW2 = NEXP * HID * INTER / 4;
    int nc = gridDim.x - nwg;
    for (int i = (lin - nwg) * 512 + threadIdx.x; i < NW2; i += nc * 512) {
      float4 v = reinterpret_cast<const float4*>(w2f)[i];
      ushort4 u;
      u.x = f2bf(v.x); u.y = f2bf(v.y); u.z = f2bf(v.z); u.w = f2bf(v.w);
      reinterpret_cast<ushort4*>(w2b)[i] = u;
    }
    return;
  }
  const int wg = xcd_swz(lin, nwg);
  const int ti = wg / 11;
  const int nt = wg - ti * 11;
  const int e = ctrl[32 + ti], mt = ctrl[104 + ti];
  const int rows = ctrl[e], off_e = ctrl[8 + e];
  const int n0g = nt * 128;
  const unsigned short* w1e = w1 + (size_t)e * (2 * INTER * HID);

  __shared__ __align__(16) char smem[3 * G1SZ];  // 72 KiB

  const int t = threadIdx.x;
  const int lane = t & 63, wv = t >> 6;
  const int wm = wv >> 2, wn = wv & 3;
  const int lm = lane & 15, hi4 = lane >> 4;
  const int wvb16 = (t & 448) * 16;
  const int arow = wm * 4096 + lm * 64;
  const int brow = 8192 + wn * 2048 + lm * 64;
  const int swz = (hi4 ^ ((lm >> 1) & 3)) * 16;

  // stage sources: global chunk pre-swizzled cl = (t&3)^((t>>3)&3) (rule #21)
  const unsigned short *aptr, *bptr0, *bptr1;
  {
    int cl8 = ((t & 3) ^ ((t >> 3) & 3)) * 8;
    int r = t >> 2;                       // 0..127
    int g0 = mt * 128 + r; if (g0 > rows - 1) g0 = rows - 1;
    aptr = hs + (size_t)row_token[off_e + g0] * HID + cl8;
    bptr0 = w1e + (size_t)(n0g + r) * HID + cl8;           // gate chans
    bptr1 = w1e + (size_t)(INTER + n0g + r) * HID + cl8;   // up chans
  }

  f32x4 accg[4][2], accu[4][2];
#pragma unroll
  for (int m = 0; m < 4; ++m)
#pragma unroll
    for (int n = 0; n < 2; ++n) {
      accg[m][n] = (f32x4){0.f, 0.f, 0.f, 0.f};
      accu[m][n] = (f32x4){0.f, 0.f, 0.f, 0.f};
    }
  bf16x8 af[4], bg[2], bu[2];

  // prologue: tile0 -> bufA, tile1 -> bufB; VM3 completes tile0 only
  unsigned bA = 0, bB = G1SZ, bC = 2 * G1SZ;
  G1_STAGE(bA, 0)
  G1_STAGE(bB, 1)
  VM3; BAR;

  for (int kt = 0; kt < NK1; ++kt) {
    G1_RD(bA)
    if (kt + 2 < NK1) { G1_STAGE(bC, kt + 2) }
    SCHED0;
    PRIO1; G1_MMA PRIO0;
    if (kt < NK1 - 2) { VM3; }
    else if (kt == NK1 - 2) { VM0; }
    LGKM0; BAR;
    unsigned tmp = bA; bA = bB; bB = bC; bC = tmp;
  }

  // SwiGLU epilogue
#pragma unroll
  for (int m = 0; m < 4; ++m)
#pragma unroll
    for (int n = 0; n < 2; ++n) {
      int col = n0g + wn * 32 + n * 16 + lm;
#pragma unroll
      for (int j = 0; j < 4; ++j) {
        int grow = mt * 128 + wm * 64 + m * 16 + hi4 * 4 + j;
        if (grow < rows) {
          float g = accg[m][n][j];
          float u = accu[m][n][j];
          float a = g / (1.0f + __expf(-g)) * u;
          act[(size_t)(off_e + grow) * INTER + col] = f2bf(a);
        }
      }
    }
}

// ================= GEMM2: down proj =================
// BM=128, BN=128, BK=32, 8 waves, TRIPLE-buffered 3 x 16 KiB = 48 KiB
// -> 3 blocks/CU. Same 1-barrier counted loop, VM2 (2 loads/tile in flight).
#define G2_STAGE(BB, kt) { \
  gload16(aptr + (size_t)(kt)*32, smem + (BB) + wvb16); \
  gload16(bptr + (size_t)(kt)*32, smem + (BB) + 8192 + wvb16); }

#define G2_RD(BB) { \
  _Pragma("unroll") for (int m_ = 0; m_ < 4; ++m_) \
    af[m_] = *(const bf16x8*)(smem + (BB) + arow + m_*1024 + swz); \
  _Pragma("unroll") for (int n_ = 0; n_ < 2; ++n_) \
    bn[n_] = *(const bf16x8*)(smem + (BB) + brow + n_*1024 + swz); }

#define G2_MMA \
  _Pragma("unroll") for (int m_ = 0; m_ < 4; ++m_) \
  _Pragma("unroll") for (int n_ = 0; n_ < 2; ++n_) \
    acc[m_][n_] = __builtin_amdgcn_mfma_f32_16x16x32_bf16(af[m_], bn[n_], acc[m_][n_], 0, 0, 0);

__global__ __launch_bounds__(512, 6) void k_gemm2(
    const unsigned short* __restrict__ act,
    const unsigned short* __restrict__ w2,
    const int* __restrict__ ctrl,
    unsigned short* __restrict__ eo) {
  const int T = ctrl[16];
  const int nwg = T * 16;
  const int lin = blockIdx.x;
  if (lin >= nwg) return;
  const int wg = xcd_swz(lin, nwg);
  const int ti = wg >> 4;
  const int nt = wg & 15;
  const int e = ctrl[32 + ti], mt = ctrl[104 + ti];
  const int rows = ctrl[e], off_e = ctrl[8 + e];
  const int n0 = nt * 128;
  const unsigned short* w2e = w2 + (size_t)e * (HID * INTER);

  __shared__ __align__(16) char smem[3 * G2SZ];  // 48 KiB

  const int t = threadIdx.x;
  const int lane = t & 63, wv = t >> 6;
  const int wm = wv >> 2, wn = wv & 3;
  const int lm = lane & 15, hi4 = lane >> 4;
  const int wvb16 = (t & 448) * 16;
  const int arow = wm * 4096 + lm * 64;
  const int brow = 8192 + wn * 2048 + lm * 64;
  const int swz = (hi4 ^ ((lm >> 1) & 3)) * 16;

  const unsigned short *aptr, *bptr;
  {
    int cl8 = ((t & 3) ^ ((t >> 3) & 3)) * 8;
    int r = t >> 2;
    int g0 = mt * 128 + r; if (g0 > rows - 1) g0 = rows - 1;
    aptr = act + (size_t)(off_e + g0) * INTER + cl8;
    bptr = w2e + (size_t)(n0 + r) * INTER + cl8;
  }

  f32x4 acc[4][2];
#pragma unroll
  for (int m = 0; m < 4; ++m)
#pragma unroll
    for (int n = 0; n < 2; ++n) acc[m][n] = (f32x4){0.f, 0.f, 0.f, 0.f};
  bf16x8 af[4], bn[2];

  unsigned bA = 0, bB = G2SZ, bC = 2 * G2SZ;
  G2_STAGE(bA, 0)
  G2_STAGE(bB, 1)
  VM2; BAR;

  for (int kt = 0; kt < NK2; ++kt) {
    G2_RD(bA)
    if (kt + 2 < NK2) { G2_STAGE(bC, kt + 2) }
    SCHED0;
    PRIO1; G2_MMA PRIO0;
    if (kt < NK2 - 2) { VM2; }
    else if (kt == NK2 - 2) { VM0; }
    LGKM0; BAR;
    unsigned tmp = bA; bA = bB; bB = bC; bC = tmp;
  }

#pragma unroll
  for (int m = 0; m < 4; ++m)
#pragma unroll
    for (int n = 0; n < 2; ++n) {
      int col = n0 + wn * 32 + n * 16 + lm;
#pragma unroll
      for (int j = 0; j < 4; ++j) {
        int grow = mt * 128 + wm * 64 + m * 16 + hi4 * 4 + j;
        if (grow < rows)
          eo[(size_t)(off_e + grow) * HID + col] = f2bf(acc[m][n][j]);
      }
    }
}

// ---------------- weighted combine: out = w0*eo[r0] + w1*eo[r1] ----------
__global__ void k_combine(const unsigned short* __restrict__ eo,
                          const float* __restrict__ tw,
                          const unsigned short* __restrict__ inv_row,
                          float* __restrict__ out) {
  int idx = blockIdx.x * blockDim.x + threadIdx.x;  // one bf16x8 chunk
  int tok = idx >> 8;        // HID/8 = 256 chunks per token
  int c8 = (idx & 255) * 8;
  int r0 = inv_row[tok * 2], r1 = inv_row[tok * 2 + 1];
  float w0 = tw[tok * 2], w1 = tw[tok * 2 + 1];
  bf16x8 v0 = *(const bf16x8*)(eo + (size_t)r0 * HID + c8);
  bf16x8 v1 = *(const bf16x8*)(eo + (size_t)r1 * HID + c8);
  float4 o0, o1;
  o0.x = w0 * bf2f((unsigned short)v0[0]) + w1 * bf2f((unsigned short)v1[0]);
  o0.y = w0 * bf2f((unsigned short)v0[1]) + w1 * bf2f((unsigned short)v1[1]);
  o0.z = w0 * bf2f((unsigned short)v0[2]) + w1 * bf2f((unsigned short)v1[2]);
  o0.w = w0 * bf2f((unsigned short)v0[3]) + w1 * bf2f((unsigned short)v1[3]);
  o1.x = w0 * bf2f((unsigned short)v0[4]) + w1 * bf2f((unsigned short)v1[4]);
  o1.y = w0 * bf2f((unsigned short)v0[5]) + w1 * bf2f((unsigned short)v1[5]);
  o1.z = w0 * bf2f((unsigned short)v0[6]) + w1 * bf2f((unsigned short)v1[6]);
  o1.w = w0 * bf2f((unsigned short)v0[7]) + w1 * bf2f((unsigned short)v1[7]);
  float4* op = reinterpret_cast<float4*>(out) + (size_t)tok * 512 + (idx & 255) * 2;
  op[0] = o0;
  op[1] = o1;
}

extern "C" void kernel_launch(void* const* d_in, const int* in_sizes, int n_in,
                              void* d_out, int out_size, void* d_ws, size_t ws_size,
                              hipStream_t stream) {
  const float* hs_f = (const float*)d_in[0];
  const float* w1_f = (const float*)d_in[1];
  const float* w2_f = (const float*)d_in[2];
  const float* tw   = (const float*)d_in[3];
  const int*   tids = (const int*)d_in[4];
  float* out = (float*)d_out;

  // workspace layout (bytes) — same proven 178,323,712-byte footprint.
  // hs_b and w1_b are contiguous so prep converts both with one index space.
  char* ws = (char*)d_ws;
  unsigned short* hs_b = (unsigned short*)(ws);                   // 16,777,216
  unsigned short* w2_b = (unsigned short*)(ws + 109051904);       // 46,137,344
  unsigned short* act  = (unsigned short*)(ws + 155189248);       // 23,068,672
  // eo overlays w1_b (dead after gemm1): 8192*2048*2 = 33,554,432 bytes
  unsigned short* eo   = (unsigned short*)(ws + 16777216);
  int* ctrl = (int*)(ws + 178257920);                             // 1024 B
  unsigned short* row_token = (unsigned short*)(ws + 178258944);  // 16,384
  unsigned short* inv_row   = (unsigned short*)(ws + 178275328);  // 16,384

  // prep: block 0 = routing; blocks 1..2048 convert hs + w1 (contiguous dst)
  k_prep<<<2049, 512, 0, stream>>>(hs_f, w1_f, hs_b, tids, ctrl, row_token, inv_row);

  // gemm1: worst-case live tiles T<=72 -> nwg<=792; remaining blocks cvt w2
  k_gemm1<<<1280, 512, 0, stream>>>(hs_b, (unsigned short*)(ws + 16777216), w2_f, w2_b,
                                    ctrl, row_token, act);
  k_gemm2<<<72 * 16, 512, 0, stream>>>(act, w2_b, ctrl, eo);
  k_combine<<<NTOK * HID / 8 / 256, 256, 0, stream>>>(eo, tw, inv_row, out);
}